// Round 7
// baseline (490.925 us; speedup 1.0000x reference)
//
#include <hip/hip_runtime.h>
#include <math.h>

#define N_NODES 50000
#define N_EDGES 1600000
#define N_GRAPH 500
#define CHUNKS 64
#define FILL_SUB 16
#define TILE_MAGIC 343598u  // ceil(2^32 / 12500): tile = floor(s/12500), exact for s < 50000
#define AGG_BLOCKS 2048
#define AGG_WAVES (AGG_BLOCKS * 4)
#define NK 7                // ceil(50000 / 8192)

// ---------- helpers ----------
__device__ __forceinline__ float rl(float v, int k) {
    return __int_as_float(__builtin_amdgcn_readlane(__float_as_int(v), k));
}

// ---------- hist: per-chunk LDS histogram (packed 2x16-bit) + local rank, no global atomics
__global__ __launch_bounds__(1024) void hist_kernel(const int* __restrict__ dst,
                                                    unsigned short* __restrict__ hist,
                                                    unsigned short* __restrict__ lr, int E) {
    __shared__ unsigned packed[N_NODES / 2];  // 100 KB
    for (int i = threadIdx.x; i < N_NODES / 2; i += 1024) packed[i] = 0;
    __syncthreads();
    int c = blockIdx.x;
    int per = E / CHUNKS;  // 25000
    int s = c * per;
    for (int e = s + threadIdx.x; e < s + per; e += 1024) {
        int d = dst[e];
        int sh = (d & 1) * 16;
        unsigned old = atomicAdd(&packed[d >> 1], 1u << sh);
        lr[e] = (unsigned short)((old >> sh) & 0xffffu);
    }
    __syncthreads();
    unsigned short* hc = hist + (size_t)c * N_NODES;
    for (int i = threadIdx.x; i < N_NODES; i += 1024) {
        unsigned w = packed[i >> 1];
        hc[i] = (unsigned short)((w >> ((i & 1) * 16)) & 0xffffu);
    }
}

// ---------- base + scan1 fused: per-node chunk-scan -> base, deg; block-sum -> part ----------
__global__ __launch_bounds__(1024) void base_scan1_kernel(const unsigned short* __restrict__ hist,
                                                          unsigned short* __restrict__ base,
                                                          int* __restrict__ deg,
                                                          int* __restrict__ part, int N) {
    int d = blockIdx.x * 1024 + threadIdx.x;
    int run = 0;
    if (d < N) {
#pragma unroll 8
        for (int c = 0; c < CHUNKS; c++) {
            int v = hist[(size_t)c * N + d];
            base[(size_t)c * N + d] = (unsigned short)run;
            run += v;
        }
        deg[d] = run;
    }
    int v = run;
#pragma unroll
    for (int o = 32; o >= 1; o >>= 1) v += __shfl_xor(v, o);
    __shared__ int red[16];
    if ((threadIdx.x & 63) == 0) red[threadIdx.x >> 6] = v;
    __syncthreads();
    if (threadIdx.x == 0) {
        int s = 0;
#pragma unroll
        for (int k = 0; k < 16; k++) s += red[k];
        part[blockIdx.x] = s;
    }
}

__global__ void scan2_kernel(int* __restrict__ part, int nb) {
    int lane = threadIdx.x;
    int v = (lane < nb) ? part[lane] : 0;
    int orig = v;
#pragma unroll
    for (int o = 1; o < 64; o <<= 1) {
        int t = __shfl_up(v, o);
        if (lane >= o) v += t;
    }
    if (lane < nb) part[lane] = v - orig;
    if (lane == nb - 1) part[nb] = v;
}

__global__ __launch_bounds__(1024) void scan3_kernel(const int* __restrict__ deg,
                                                     const int* __restrict__ part,
                                                     int* __restrict__ rowptr, int N) {
    int i = blockIdx.x * 1024 + threadIdx.x;
    int lane = threadIdx.x & 63;
    int w = threadIdx.x >> 6;
    int v = (i < N) ? deg[i] : 0;
    int inc = v;
#pragma unroll
    for (int o = 1; o < 64; o <<= 1) {
        int t = __shfl_up(inc, o);
        if (lane >= o) inc += t;
    }
    __shared__ int wsum[16];
    if (lane == 63) wsum[w] = inc;
    __syncthreads();
    if (threadIdx.x < 16) {
        int x = wsum[threadIdx.x];
        int xo = x;
#pragma unroll
        for (int o = 1; o < 16; o <<= 1) {
            int t = __shfl_up(x, o);
            if ((int)threadIdx.x >= o) x += t;
        }
        wsum[threadIdx.x] = x - xo;
    }
    __syncthreads();
    int b = part[blockIdx.x] + wsum[w];
    if (i < N) {
        rowptr[i] = b + inc - v;
        if (i == N - 1) rowptr[N] = b + inc;
    }
}

// ---------- fill: atomic-free scatter via rowptr + base + lr ----------
__global__ __launch_bounds__(256) void fill_kernel(const int* __restrict__ src,
                                                   const int* __restrict__ dst,
                                                   const unsigned short* __restrict__ lr,
                                                   const unsigned short* __restrict__ base,
                                                   const int* __restrict__ rowptr,
                                                   int* __restrict__ csr_src, int E) {
    int c = blockIdx.x / FILL_SUB;
    int s = blockIdx.x % FILL_SUB;
    int per = E / CHUNKS;
    int e0 = c * per + (s * per) / FILL_SUB;
    int e1 = c * per + ((s + 1) * per) / FILL_SUB;
    const unsigned short* basec = base + (size_t)c * N_NODES;
    for (int e = e0 + threadIdx.x; e < e1; e += 256) {
        int d = dst[e];
        int pos = rowptr[d] + (int)basec[d] + (int)lr[e];
        csr_src[pos] = src[e];
    }
}

// ---------- sort_csr: per-node ballot counting-sort of edge list into 4 src-tiles ----------
__global__ __launch_bounds__(256) void sort_csr_kernel(int* __restrict__ csr_src,
                                                       const int* __restrict__ rowptr,
                                                       uchar4* __restrict__ splits, int N) {
    int wid = (blockIdx.x * 256 + threadIdx.x) >> 6;
    int lane = threadIdx.x & 63;
    if (wid >= N) return;
    int start = rowptr[wid];
    int deg = rowptr[wid + 1] - start;
    if (deg > 128) {  // fallback: whole (unsorted) list processed in phase 3
        if (lane == 0) splits[wid] = make_uchar4(0, 0, 0, 0);
        return;
    }
    bool vA = lane < deg;
    bool vB = 64 + lane < deg;
    int eA = vA ? csr_src[start + lane] : 0;
    int eB = vB ? csr_src[start + 64 + lane] : 0;
    int tA = (int)__umulhi((unsigned)eA, TILE_MAGIC);
    int tB = (int)__umulhi((unsigned)eB, TILE_MAGIC);
    unsigned long long mA[4], mB[4];
#pragma unroll
    for (int t = 0; t < 4; t++) {
        mA[t] = __ballot(vA && tA == t);
        mB[t] = __ballot(vB && tB == t);
    }
    int base[4];
    int run = 0;
#pragma unroll
    for (int t = 0; t < 4; t++) {
        base[t] = run;
        run += __popcll(mA[t]) + __popcll(mB[t]);
    }
    unsigned long long lt = ((unsigned long long)1 << lane) - 1;
    if (vA) {
        int p = base[tA] + (int)__popcll(mA[tA] & lt);
        csr_src[start + p] = eA;
    }
    if (vB) {
        int p = base[tB] + (int)__popcll(mA[tB]) + (int)__popcll(mB[tB] & lt);
        csr_src[start + p] = eB;
    }
    if (lane == 0)
        splits[wid] = make_uchar4((unsigned char)base[1], (unsigned char)base[2],
                                  (unsigned char)base[3], 0);
}

// ---------- agg4: 4 free-running src-tile phases, register accumulators ----------
__global__ __launch_bounds__(256, 8) void agg4_kernel(const float* __restrict__ y,
                                                      const int* __restrict__ rowptr,
                                                      const int* __restrict__ csr_src,
                                                      const uchar4* __restrict__ splits,
                                                      float* __restrict__ u, int N) {
    int gw = (blockIdx.x * 256 + threadIdx.x) >> 6;
    int lane = threadIdx.x & 63;
    int q = lane >> 4;          // edge slot 0..3
    int r = (lane & 15) * 4;    // feature offset
    float4 acc[NK];
#pragma unroll
    for (int k = 0; k < NK; k++) acc[k] = make_float4(0.f, 0.f, 0.f, 0.f);

#pragma unroll 1
    for (int t = 0; t < 4; t++) {
#pragma unroll
        for (int k = 0; k < NK; k++) {
            int n = gw + k * AGG_WAVES;
            if (n < N) {
                int st = rowptr[n];
                int dend = rowptr[n + 1];
                uchar4 c = splits[n];
                int c0 = c.x, c1 = c.y, c2 = c.z;
                int cbt = (t == 0) ? 0 : (t == 1) ? c0 : (t == 2) ? c1 : c2;
                int cbt1 = (t == 0) ? c0 : (t == 1) ? c1 : (t == 2) ? c2 : (dend - st);
                int lo = st + cbt, hi = st + cbt1;
                float4 a = acc[k];
                for (int j = lo; j < hi; j += 16) {
#pragma unroll
                    for (int m2 = 0; m2 < 4; m2++) {
                        int e = j + 4 * m2 + q;
                        if (e < hi) {
                            int s = csr_src[e];
                            float4 v = *(const float4*)(y + (size_t)s * 64 + r);
                            a.x += v.x; a.y += v.y; a.z += v.z; a.w += v.w;
                        }
                    }
                }
                if (q == 0 && (int)__umulhi((unsigned)n, TILE_MAGIC) == t) {
                    float4 v = *(const float4*)(y + (size_t)n * 64 + r);
                    a.x += v.x; a.y += v.y; a.z += v.z; a.w += v.w;
                }
                acc[k] = a;
            }
        }
    }
#pragma unroll
    for (int k = 0; k < NK; k++) {
        int n = gw + k * AGG_WAVES;
        if (n < N) {
            float4 a = acc[k];
            a.x += __shfl_xor(a.x, 16); a.y += __shfl_xor(a.y, 16);
            a.z += __shfl_xor(a.z, 16); a.w += __shfl_xor(a.w, 16);
            a.x += __shfl_xor(a.x, 32); a.y += __shfl_xor(a.y, 32);
            a.z += __shfl_xor(a.z, 32); a.w += __shfl_xor(a.w, 32);
            if (lane < 16) *(float4*)(u + (size_t)n * 64 + r) = a;
        }
    }
}

// ---------- gemm0: y0 = x @ W1_0 (N x 128 -> N x 64), register weights ----------
__global__ __launch_bounds__(256) void gemm0_kernel(const float* __restrict__ x,
                                                    const float* __restrict__ W1,
                                                    float* __restrict__ y0,
                                                    int N, int totalWaves) {
    int lane = threadIdx.x & 63;
    int wid = (blockIdx.x * 256 + threadIdx.x) >> 6;
    float w[64];
#pragma unroll
    for (int k = 0; k < 64; k++) w[k] = W1[k * 64 + lane];
    for (int node = wid; node < N; node += totalWaves) {
        float xa = x[node * 128 + lane];
        float a0 = 0.f, a1 = 0.f, a2 = 0.f, a3 = 0.f;
#pragma unroll
        for (int k = 0; k < 64; k += 4) {
            a0 = fmaf(rl(xa, k + 0), w[k + 0], a0);
            a1 = fmaf(rl(xa, k + 1), w[k + 1], a1);
            a2 = fmaf(rl(xa, k + 2), w[k + 2], a2);
            a3 = fmaf(rl(xa, k + 3), w[k + 3], a3);
        }
        y0[node * 64 + lane] = (a0 + a1) + (a2 + a3);
    }
#pragma unroll
    for (int k = 0; k < 64; k++) w[k] = W1[(64 + k) * 64 + lane];
    for (int node = wid; node < N; node += totalWaves) {
        float xb = x[node * 128 + 64 + lane];
        float a0 = 0.f, a1 = 0.f, a2 = 0.f, a3 = 0.f;
#pragma unroll
        for (int k = 0; k < 64; k += 4) {
            a0 = fmaf(rl(xb, k + 0), w[k + 0], a0);
            a1 = fmaf(rl(xb, k + 1), w[k + 1], a1);
            a2 = fmaf(rl(xb, k + 2), w[k + 2], a2);
            a3 = fmaf(rl(xb, k + 3), w[k + 3], a3);
        }
        y0[node * 64 + lane] += (a0 + a1) + (a2 + a3);
    }
}

// ---------- fused mlpAB (layers 0,1) ----------
template <int LAYER>
__global__ __launch_bounds__(256) void mlpAB_kernel(const float* __restrict__ u,
                                                    const float* __restrict__ b1,
                                                    const float* __restrict__ W2,
                                                    const float* __restrict__ b2,
                                                    const float* __restrict__ W1n,
                                                    const float* __restrict__ Wm,
                                                    float* __restrict__ ynext,
                                                    float* __restrict__ score,
                                                    int N, int totalWaves) {
    int lane = threadIdx.x & 63;
    int wid = (blockIdx.x * 256 + threadIdx.x) >> 6;
    float w2[64], w1[64];
#pragma unroll
    for (int k = 0; k < 64; k++) w2[k] = W2[k * 64 + lane];
#pragma unroll
    for (int k = 0; k < 64; k++) w1[k] = W1n[k * 64 + lane];
    float bb1 = b1[lane], bb2 = b2[lane], wm = Wm[LAYER * 64 + lane];

    int node = wid;
    float uin = (node < N) ? u[node * 64 + lane] : 0.f;
    for (; node < N; node += totalWaves) {
        int nn = node + totalWaves;
        float unext = (nn < N) ? u[nn * 64 + lane] : 0.f;
        float t = fmaxf(uin + bb1, 0.f);
        float a0 = 0.f, a1 = 0.f, a2 = 0.f, a3 = 0.f;
#pragma unroll
        for (int k = 0; k < 64; k += 4) {
            a0 = fmaf(rl(t, k + 0), w2[k + 0], a0);
            a1 = fmaf(rl(t, k + 1), w2[k + 1], a1);
            a2 = fmaf(rl(t, k + 2), w2[k + 2], a2);
            a3 = fmaf(rl(t, k + 3), w2[k + 3], a3);
        }
        float h = fmaxf(bb2 + ((a0 + a1) + (a2 + a3)), 0.f);
        float p = h * wm;
#pragma unroll
        for (int o = 32; o >= 1; o >>= 1) p += __shfl_xor(p, o);
        if (lane == 0) {
            if (LAYER == 0) score[node] = p;
            else score[node] += p;
        }
        float y0 = 0.f, y1 = 0.f, y2 = 0.f, y3 = 0.f;
#pragma unroll
        for (int k = 0; k < 64; k += 4) {
            y0 = fmaf(rl(h, k + 0), w1[k + 0], y0);
            y1 = fmaf(rl(h, k + 1), w1[k + 1], y1);
            y2 = fmaf(rl(h, k + 2), w1[k + 2], y2);
            y3 = fmaf(rl(h, k + 3), w1[k + 3], y3);
        }
        ynext[node * 64 + lane] = (y0 + y1) + (y2 + y3);
        uin = unext;
    }
}

// ---------- mlpA2 (layer 2) ----------
__global__ __launch_bounds__(256) void mlpA2_kernel(const float* __restrict__ u,
                                                    const float* __restrict__ b1,
                                                    const float* __restrict__ W2,
                                                    const float* __restrict__ b2,
                                                    const float* __restrict__ Wm,
                                                    float* __restrict__ score,
                                                    int N, int totalWaves) {
    int lane = threadIdx.x & 63;
    int wid = (blockIdx.x * 256 + threadIdx.x) >> 6;
    float w2[64];
#pragma unroll
    for (int k = 0; k < 64; k++) w2[k] = W2[k * 64 + lane];
    float bb1 = b1[lane], bb2 = b2[lane], wm = Wm[2 * 64 + lane];

    int node = wid;
    float uin = (node < N) ? u[node * 64 + lane] : 0.f;
    for (; node < N; node += totalWaves) {
        int nn = node + totalWaves;
        float unext = (nn < N) ? u[nn * 64 + lane] : 0.f;
        float t = fmaxf(uin + bb1, 0.f);
        float a0 = 0.f, a1 = 0.f, a2 = 0.f, a3 = 0.f;
#pragma unroll
        for (int k = 0; k < 64; k += 4) {
            a0 = fmaf(rl(t, k + 0), w2[k + 0], a0);
            a1 = fmaf(rl(t, k + 1), w2[k + 1], a1);
            a2 = fmaf(rl(t, k + 2), w2[k + 2], a2);
            a3 = fmaf(rl(t, k + 3), w2[k + 3], a3);
        }
        float h = bb2 + ((a0 + a1) + (a2 + a3));
        float p = h * wm;
#pragma unroll
        for (int o = 32; o >= 1; o >>= 1) p += __shfl_xor(p, o);
        if (lane == 0) score[node] += p;
        uin = unext;
    }
}

// ---------- edge softmax + new_score ----------
__global__ __launch_bounds__(256) void edge_softmax_kernel(const float* __restrict__ score,
                                                           const int* __restrict__ rowptr,
                                                           const int* __restrict__ csr_src,
                                                           const float* __restrict__ bm,
                                                           float* __restrict__ nsf, int N) {
    int wid = (blockIdx.x * blockDim.x + threadIdx.x) >> 6;
    int lane = threadIdx.x & 63;
    if (wid >= N) return;
    float b = bm[0];
    float sd = score[wid] + b;
    int start = rowptr[wid];
    int end = rowptr[wid + 1];
    bool has0 = (start + lane < end);
    float ss0 = 0.f;
    float m = -INFINITY;
    if (has0) {
        ss0 = score[csr_src[start + lane]] + b;
        m = ss0 * sd;
    }
    for (int j = start + 64 + lane; j < end; j += 64) {
        float ss = score[csr_src[j]] + b;
        m = fmaxf(m, ss * sd);
    }
#pragma unroll
    for (int o = 32; o >= 1; o >>= 1) m = fmaxf(m, __shfl_xor(m, o));
    float se = 0.f, swe = 0.f;
    if (m > -INFINITY) {
        if (has0) {
            float e0 = expf(ss0 * sd - m);
            se += e0;
            swe += ss0 * e0;
        }
        for (int j = start + 64 + lane; j < end; j += 64) {
            float ss = score[csr_src[j]] + b;
            float e = expf(ss * sd - m);
            se += e;
            swe += ss * e;
        }
#pragma unroll
        for (int o = 32; o >= 1; o >>= 1) {
            se += __shfl_xor(se, o);
            swe += __shfl_xor(swe, o);
        }
    }
    float ns = (se > 0.f) ? (swe / se) : 0.f;
    if (lane == 0) nsf[wid] = sd + ns;
}

// ---------- fused graph-segment softmax: one block per graph ----------
__global__ __launch_bounds__(256) void graph_softmax_kernel(const float* __restrict__ nsf,
                                                            const int* __restrict__ batch,
                                                            float* __restrict__ out, int N) {
    int g = blockIdx.x;
    int tid = threadIdx.x;
    int lo = 0, hi = N;
    while (lo < hi) { int mid = (lo + hi) >> 1; if (batch[mid] < g) lo = mid + 1; else hi = mid; }
    int s0 = lo;
    hi = N;
    while (lo < hi) { int mid = (lo + hi) >> 1; if (batch[mid] < g + 1) lo = mid + 1; else hi = mid; }
    int s1 = lo;

    __shared__ float red[4];
    __shared__ float bval;
    float m = -INFINITY;
    for (int i = s0 + tid; i < s1; i += 256) m = fmaxf(m, nsf[i]);
#pragma unroll
    for (int o = 32; o >= 1; o >>= 1) m = fmaxf(m, __shfl_xor(m, o));
    if ((tid & 63) == 0) red[tid >> 6] = m;
    __syncthreads();
    if (tid == 0) bval = fmaxf(fmaxf(red[0], red[1]), fmaxf(red[2], red[3]));
    __syncthreads();
    float bm = bval;
    float s = 0.f;
    for (int i = s0 + tid; i < s1; i += 256) {
        float e = expf(nsf[i] - bm);
        out[i] = e;
        s += e;
    }
#pragma unroll
    for (int o = 32; o >= 1; o >>= 1) s += __shfl_xor(s, o);
    __syncthreads();
    if ((tid & 63) == 0) red[tid >> 6] = s;
    __syncthreads();
    if (tid == 0) bval = red[0] + red[1] + red[2] + red[3];
    __syncthreads();
    float inv = 1.f / bval;
    for (int i = s0 + tid; i < s1; i += 256) out[i] *= inv;
}

extern "C" void kernel_launch(void* const* d_in, const int* in_sizes, int n_in,
                              void* d_out, int out_size, void* d_ws, size_t ws_size,
                              hipStream_t stream) {
    const int N = N_NODES, E = N_EDGES;

    const float* x = (const float*)d_in[0];
    const int* ei = (const int*)d_in[1];
    const int* batch = (const int*)d_in[2];
    const float* W1a[3] = {(const float*)d_in[3], (const float*)d_in[7], (const float*)d_in[11]};
    const float* b1a[3] = {(const float*)d_in[4], (const float*)d_in[8], (const float*)d_in[12]};
    const float* W2a[3] = {(const float*)d_in[5], (const float*)d_in[9], (const float*)d_in[13]};
    const float* b2a[3] = {(const float*)d_in[6], (const float*)d_in[10], (const float*)d_in[14]};
    const float* Wm = (const float*)d_in[15];
    const float* bm = (const float*)d_in[16];
    float* out = (float*)d_out;

    const int* srcp = ei;
    const int* dstp = ei + E;

    // workspace layout (~62 MB)
    float* yA = (float*)d_ws;                   // N*64
    float* yB = yA + (size_t)N * 64;            // N*64
    float* ubuf = yB + (size_t)N * 64;          // N*64
    float* score = ubuf + (size_t)N * 64;       // N
    float* nsf = score + N;                     // N
    int* deg = (int*)(nsf + N);                 // N
    int* rowptr = deg + N;                      // N+1
    int* part = rowptr + N + 1;                 // 64
    int* csr_src = part + 64;                   // E
    uchar4* splits = (uchar4*)(csr_src + E);                      // N
    unsigned short* lr = (unsigned short*)(splits + N);           // E
    unsigned short* hist = lr + E;                                // CHUNKS*N
    unsigned short* base = hist + (size_t)CHUNKS * N;             // CHUNKS*N

    hist_kernel<<<CHUNKS, 1024, 0, stream>>>(dstp, hist, lr, E);

    const int nbScan = (N + 1023) / 1024;  // 49
    base_scan1_kernel<<<nbScan, 1024, 0, stream>>>(hist, base, deg, part, N);
    scan2_kernel<<<1, 64, 0, stream>>>(part, nbScan);
    scan3_kernel<<<nbScan, 1024, 0, stream>>>(deg, part, rowptr, N);

    fill_kernel<<<CHUNKS * FILL_SUB, 256, 0, stream>>>(srcp, dstp, lr, base, rowptr, csr_src, E);
    sort_csr_kernel<<<(N + 3) / 4, 256, 0, stream>>>(csr_src, rowptr, splits, N);

    const int gw = 4096;
    gemm0_kernel<<<1024, 256, 0, stream>>>(x, W1a[0], yA, N, gw);

    agg4_kernel<<<AGG_BLOCKS, 256, 0, stream>>>(yA, rowptr, csr_src, splits, ubuf, N);
    mlpAB_kernel<0><<<1024, 256, 0, stream>>>(ubuf, b1a[0], W2a[0], b2a[0], W1a[1], Wm, yB, score, N, gw);

    agg4_kernel<<<AGG_BLOCKS, 256, 0, stream>>>(yB, rowptr, csr_src, splits, ubuf, N);
    mlpAB_kernel<1><<<1024, 256, 0, stream>>>(ubuf, b1a[1], W2a[1], b2a[1], W1a[2], Wm, yA, score, N, gw);

    agg4_kernel<<<AGG_BLOCKS, 256, 0, stream>>>(yA, rowptr, csr_src, splits, ubuf, N);
    mlpA2_kernel<<<1024, 256, 0, stream>>>(ubuf, b1a[2], W2a[2], b2a[2], Wm, score, N, gw);

    edge_softmax_kernel<<<(N + 3) / 4, 256, 0, stream>>>(score, rowptr, csr_src, bm, nsf, N);

    graph_softmax_kernel<<<N_GRAPH, 256, 0, stream>>>(nsf, batch, out, N);
}

// Round 8
// 430.987 us; speedup vs baseline: 1.1391x; 1.1391x over previous
//
#include <hip/hip_runtime.h>
#include <math.h>

#define N_NODES 50000
#define N_EDGES 1600000
#define N_GRAPH 500
#define CHUNKS 64
#define FILL_SUB 16
#define TILE_MAGIC 343598u  // ceil(2^32 / 12500): tile = floor(s/12500), exact for s < 50000
#define AGG_BLOCKS 4096
#define AGG_WAVES (AGG_BLOCKS * 4)
#define NK 4                // ceil(50000 / 16384)

// ---------- helpers ----------
__device__ __forceinline__ float rl(float v, int k) {
    return __int_as_float(__builtin_amdgcn_readlane(__float_as_int(v), k));
}

// ---------- hist: per-chunk LDS histogram (packed 2x16-bit) + local rank, no global atomics
__global__ __launch_bounds__(1024) void hist_kernel(const int* __restrict__ dst,
                                                    unsigned short* __restrict__ hist,
                                                    unsigned short* __restrict__ lr, int E) {
    __shared__ unsigned packed[N_NODES / 2];  // 100 KB
    for (int i = threadIdx.x; i < N_NODES / 2; i += 1024) packed[i] = 0;
    __syncthreads();
    int c = blockIdx.x;
    int per = E / CHUNKS;  // 25000
    int s = c * per;
    for (int e = s + threadIdx.x; e < s + per; e += 1024) {
        int d = dst[e];
        int sh = (d & 1) * 16;
        unsigned old = atomicAdd(&packed[d >> 1], 1u << sh);
        lr[e] = (unsigned short)((old >> sh) & 0xffffu);
    }
    __syncthreads();
    unsigned short* hc = hist + (size_t)c * N_NODES;
    for (int i = threadIdx.x; i < N_NODES; i += 1024) {
        unsigned w = packed[i >> 1];
        hc[i] = (unsigned short)((w >> ((i & 1) * 16)) & 0xffffu);
    }
}

// ---------- base + scan1 fused ----------
__global__ __launch_bounds__(1024) void base_scan1_kernel(const unsigned short* __restrict__ hist,
                                                          unsigned short* __restrict__ base,
                                                          int* __restrict__ deg,
                                                          int* __restrict__ part, int N) {
    int d = blockIdx.x * 1024 + threadIdx.x;
    int run = 0;
    if (d < N) {
#pragma unroll 8
        for (int c = 0; c < CHUNKS; c++) {
            int v = hist[(size_t)c * N + d];
            base[(size_t)c * N + d] = (unsigned short)run;
            run += v;
        }
        deg[d] = run;
    }
    int v = run;
#pragma unroll
    for (int o = 32; o >= 1; o >>= 1) v += __shfl_xor(v, o);
    __shared__ int red[16];
    if ((threadIdx.x & 63) == 0) red[threadIdx.x >> 6] = v;
    __syncthreads();
    if (threadIdx.x == 0) {
        int s = 0;
#pragma unroll
        for (int k = 0; k < 16; k++) s += red[k];
        part[blockIdx.x] = s;
    }
}

__global__ void scan2_kernel(int* __restrict__ part, int nb) {
    int lane = threadIdx.x;
    int v = (lane < nb) ? part[lane] : 0;
    int orig = v;
#pragma unroll
    for (int o = 1; o < 64; o <<= 1) {
        int t = __shfl_up(v, o);
        if (lane >= o) v += t;
    }
    if (lane < nb) part[lane] = v - orig;
    if (lane == nb - 1) part[nb] = v;
}

__global__ __launch_bounds__(1024) void scan3_kernel(const int* __restrict__ deg,
                                                     const int* __restrict__ part,
                                                     int* __restrict__ rowptr, int N) {
    int i = blockIdx.x * 1024 + threadIdx.x;
    int lane = threadIdx.x & 63;
    int w = threadIdx.x >> 6;
    int v = (i < N) ? deg[i] : 0;
    int inc = v;
#pragma unroll
    for (int o = 1; o < 64; o <<= 1) {
        int t = __shfl_up(inc, o);
        if (lane >= o) inc += t;
    }
    __shared__ int wsum[16];
    if (lane == 63) wsum[w] = inc;
    __syncthreads();
    if (threadIdx.x < 16) {
        int x = wsum[threadIdx.x];
        int xo = x;
#pragma unroll
        for (int o = 1; o < 16; o <<= 1) {
            int t = __shfl_up(x, o);
            if ((int)threadIdx.x >= o) x += t;
        }
        wsum[threadIdx.x] = x - xo;
    }
    __syncthreads();
    int b = part[blockIdx.x] + wsum[w];
    if (i < N) {
        rowptr[i] = b + inc - v;
        if (i == N - 1) rowptr[N] = b + inc;
    }
}

// ---------- fill: atomic-free scatter via rowptr + base + lr ----------
__global__ __launch_bounds__(256) void fill_kernel(const int* __restrict__ src,
                                                   const int* __restrict__ dst,
                                                   const unsigned short* __restrict__ lr,
                                                   const unsigned short* __restrict__ base,
                                                   const int* __restrict__ rowptr,
                                                   int* __restrict__ csr_src, int E) {
    int c = blockIdx.x / FILL_SUB;
    int s = blockIdx.x % FILL_SUB;
    int per = E / CHUNKS;
    int e0 = c * per + (s * per) / FILL_SUB;
    int e1 = c * per + ((s + 1) * per) / FILL_SUB;
    const unsigned short* basec = base + (size_t)c * N_NODES;
    for (int e = e0 + threadIdx.x; e < e1; e += 256) {
        int d = dst[e];
        int pos = rowptr[d] + (int)basec[d] + (int)lr[e];
        csr_src[pos] = src[e];
    }
}

// ---------- sort_csr: per-node ballot counting-sort of edge list into 4 src-tiles ----------
__global__ __launch_bounds__(256) void sort_csr_kernel(int* __restrict__ csr_src,
                                                       const int* __restrict__ rowptr,
                                                       uchar4* __restrict__ splits, int N) {
    int wid = (blockIdx.x * 256 + threadIdx.x) >> 6;
    int lane = threadIdx.x & 63;
    if (wid >= N) return;
    int start = rowptr[wid];
    int deg = rowptr[wid + 1] - start;
    if (deg > 128) {  // fallback: whole (unsorted) list processed in phase 3
        if (lane == 0) splits[wid] = make_uchar4(0, 0, 0, 0);
        return;
    }
    bool vA = lane < deg;
    bool vB = 64 + lane < deg;
    int eA = vA ? csr_src[start + lane] : 0;
    int eB = vB ? csr_src[start + 64 + lane] : 0;
    int tA = (int)__umulhi((unsigned)eA, TILE_MAGIC);
    int tB = (int)__umulhi((unsigned)eB, TILE_MAGIC);
    unsigned long long mA[4], mB[4];
#pragma unroll
    for (int t = 0; t < 4; t++) {
        mA[t] = __ballot(vA && tA == t);
        mB[t] = __ballot(vB && tB == t);
    }
    int base[4];
    int run = 0;
#pragma unroll
    for (int t = 0; t < 4; t++) {
        base[t] = run;
        run += __popcll(mA[t]) + __popcll(mB[t]);
    }
    unsigned long long lt = ((unsigned long long)1 << lane) - 1;
    if (vA) {
        int p = base[tA] + (int)__popcll(mA[tA] & lt);
        csr_src[start + p] = eA;
    }
    if (vB) {
        int p = base[tB] + (int)__popcll(mA[tB]) + (int)__popcll(mB[tB] & lt);
        csr_src[start + p] = eB;
    }
    if (lane == 0)
        splits[wid] = make_uchar4((unsigned char)base[1], (unsigned char)base[2],
                                  (unsigned char)base[3], 0);
}

// ---------- agg4: 4 free-running src-tile phases, register accumulators (NK=4, no spill) ----------
__global__ __launch_bounds__(256, 4) void agg4_kernel(const float* __restrict__ y,
                                                      const int* __restrict__ rowptr,
                                                      const int* __restrict__ csr_src,
                                                      const uchar4* __restrict__ splits,
                                                      float* __restrict__ u, int N) {
    int gw = (blockIdx.x * 256 + threadIdx.x) >> 6;
    int lane = threadIdx.x & 63;
    int q = lane >> 4;          // edge slot 0..3
    int r = (lane & 15) * 4;    // feature offset
    float4 acc[NK];
#pragma unroll
    for (int k = 0; k < NK; k++) acc[k] = make_float4(0.f, 0.f, 0.f, 0.f);

#pragma unroll 1
    for (int t = 0; t < 4; t++) {
#pragma unroll
        for (int k = 0; k < NK; k++) {
            int n = gw + k * AGG_WAVES;
            if (n < N) {
                int st = rowptr[n];
                int dend = rowptr[n + 1];
                uchar4 c = splits[n];
                int c0 = c.x, c1 = c.y, c2 = c.z;
                int cbt = (t == 0) ? 0 : (t == 1) ? c0 : (t == 2) ? c1 : c2;
                int cbt1 = (t == 0) ? c0 : (t == 1) ? c1 : (t == 2) ? c2 : (dend - st);
                int lo = st + cbt, hi = st + cbt1;
                float4 a = acc[k];
                for (int j = lo; j < hi; j += 16) {
#pragma unroll
                    for (int m2 = 0; m2 < 4; m2++) {
                        int e = j + 4 * m2 + q;
                        if (e < hi) {
                            int s = csr_src[e];
                            float4 v = *(const float4*)(y + (size_t)s * 64 + r);
                            a.x += v.x; a.y += v.y; a.z += v.z; a.w += v.w;
                        }
                    }
                }
                if (q == 0 && (int)__umulhi((unsigned)n, TILE_MAGIC) == t) {
                    float4 v = *(const float4*)(y + (size_t)n * 64 + r);
                    a.x += v.x; a.y += v.y; a.z += v.z; a.w += v.w;
                }
                acc[k] = a;
            }
        }
    }
#pragma unroll
    for (int k = 0; k < NK; k++) {
        int n = gw + k * AGG_WAVES;
        if (n < N) {
            float4 a = acc[k];
            a.x += __shfl_xor(a.x, 16); a.y += __shfl_xor(a.y, 16);
            a.z += __shfl_xor(a.z, 16); a.w += __shfl_xor(a.w, 16);
            a.x += __shfl_xor(a.x, 32); a.y += __shfl_xor(a.y, 32);
            a.z += __shfl_xor(a.z, 32); a.w += __shfl_xor(a.w, 32);
            if (lane < 16) *(float4*)(u + (size_t)n * 64 + r) = a;
        }
    }
}

// ---------- gemm0: y0 = x @ W1_0 (N x 128 -> N x 64), register weights ----------
__global__ __launch_bounds__(256) void gemm0_kernel(const float* __restrict__ x,
                                                    const float* __restrict__ W1,
                                                    float* __restrict__ y0,
                                                    int N, int totalWaves) {
    int lane = threadIdx.x & 63;
    int wid = (blockIdx.x * 256 + threadIdx.x) >> 6;
    float w[64];
#pragma unroll
    for (int k = 0; k < 64; k++) w[k] = W1[k * 64 + lane];
    for (int node = wid; node < N; node += totalWaves) {
        float xa = x[node * 128 + lane];
        float a0 = 0.f, a1 = 0.f, a2 = 0.f, a3 = 0.f;
#pragma unroll
        for (int k = 0; k < 64; k += 4) {
            a0 = fmaf(rl(xa, k + 0), w[k + 0], a0);
            a1 = fmaf(rl(xa, k + 1), w[k + 1], a1);
            a2 = fmaf(rl(xa, k + 2), w[k + 2], a2);
            a3 = fmaf(rl(xa, k + 3), w[k + 3], a3);
        }
        y0[node * 64 + lane] = (a0 + a1) + (a2 + a3);
    }
#pragma unroll
    for (int k = 0; k < 64; k++) w[k] = W1[(64 + k) * 64 + lane];
    for (int node = wid; node < N; node += totalWaves) {
        float xb = x[node * 128 + 64 + lane];
        float a0 = 0.f, a1 = 0.f, a2 = 0.f, a3 = 0.f;
#pragma unroll
        for (int k = 0; k < 64; k += 4) {
            a0 = fmaf(rl(xb, k + 0), w[k + 0], a0);
            a1 = fmaf(rl(xb, k + 1), w[k + 1], a1);
            a2 = fmaf(rl(xb, k + 2), w[k + 2], a2);
            a3 = fmaf(rl(xb, k + 3), w[k + 3], a3);
        }
        y0[node * 64 + lane] += (a0 + a1) + (a2 + a3);
    }
}

// ---------- fused mlpAB (layers 0,1) ----------
template <int LAYER>
__global__ __launch_bounds__(256) void mlpAB_kernel(const float* __restrict__ u,
                                                    const float* __restrict__ b1,
                                                    const float* __restrict__ W2,
                                                    const float* __restrict__ b2,
                                                    const float* __restrict__ W1n,
                                                    const float* __restrict__ Wm,
                                                    float* __restrict__ ynext,
                                                    float* __restrict__ score,
                                                    int N, int totalWaves) {
    int lane = threadIdx.x & 63;
    int wid = (blockIdx.x * 256 + threadIdx.x) >> 6;
    float w2[64], w1[64];
#pragma unroll
    for (int k = 0; k < 64; k++) w2[k] = W2[k * 64 + lane];
#pragma unroll
    for (int k = 0; k < 64; k++) w1[k] = W1n[k * 64 + lane];
    float bb1 = b1[lane], bb2 = b2[lane], wm = Wm[LAYER * 64 + lane];

    int node = wid;
    float uin = (node < N) ? u[node * 64 + lane] : 0.f;
    for (; node < N; node += totalWaves) {
        int nn = node + totalWaves;
        float unext = (nn < N) ? u[nn * 64 + lane] : 0.f;
        float t = fmaxf(uin + bb1, 0.f);
        float a0 = 0.f, a1 = 0.f, a2 = 0.f, a3 = 0.f;
#pragma unroll
        for (int k = 0; k < 64; k += 4) {
            a0 = fmaf(rl(t, k + 0), w2[k + 0], a0);
            a1 = fmaf(rl(t, k + 1), w2[k + 1], a1);
            a2 = fmaf(rl(t, k + 2), w2[k + 2], a2);
            a3 = fmaf(rl(t, k + 3), w2[k + 3], a3);
        }
        float h = fmaxf(bb2 + ((a0 + a1) + (a2 + a3)), 0.f);
        float p = h * wm;
#pragma unroll
        for (int o = 32; o >= 1; o >>= 1) p += __shfl_xor(p, o);
        if (lane == 0) {
            if (LAYER == 0) score[node] = p;
            else score[node] += p;
        }
        float y0 = 0.f, y1 = 0.f, y2 = 0.f, y3 = 0.f;
#pragma unroll
        for (int k = 0; k < 64; k += 4) {
            y0 = fmaf(rl(h, k + 0), w1[k + 0], y0);
            y1 = fmaf(rl(h, k + 1), w1[k + 1], y1);
            y2 = fmaf(rl(h, k + 2), w1[k + 2], y2);
            y3 = fmaf(rl(h, k + 3), w1[k + 3], y3);
        }
        ynext[node * 64 + lane] = (y0 + y1) + (y2 + y3);
        uin = unext;
    }
}

// ---------- mlpA2 (layer 2) ----------
__global__ __launch_bounds__(256) void mlpA2_kernel(const float* __restrict__ u,
                                                    const float* __restrict__ b1,
                                                    const float* __restrict__ W2,
                                                    const float* __restrict__ b2,
                                                    const float* __restrict__ Wm,
                                                    float* __restrict__ score,
                                                    int N, int totalWaves) {
    int lane = threadIdx.x & 63;
    int wid = (blockIdx.x * 256 + threadIdx.x) >> 6;
    float w2[64];
#pragma unroll
    for (int k = 0; k < 64; k++) w2[k] = W2[k * 64 + lane];
    float bb1 = b1[lane], bb2 = b2[lane], wm = Wm[2 * 64 + lane];

    int node = wid;
    float uin = (node < N) ? u[node * 64 + lane] : 0.f;
    for (; node < N; node += totalWaves) {
        int nn = node + totalWaves;
        float unext = (nn < N) ? u[nn * 64 + lane] : 0.f;
        float t = fmaxf(uin + bb1, 0.f);
        float a0 = 0.f, a1 = 0.f, a2 = 0.f, a3 = 0.f;
#pragma unroll
        for (int k = 0; k < 64; k += 4) {
            a0 = fmaf(rl(t, k + 0), w2[k + 0], a0);
            a1 = fmaf(rl(t, k + 1), w2[k + 1], a1);
            a2 = fmaf(rl(t, k + 2), w2[k + 2], a2);
            a3 = fmaf(rl(t, k + 3), w2[k + 3], a3);
        }
        float h = bb2 + ((a0 + a1) + (a2 + a3));
        float p = h * wm;
#pragma unroll
        for (int o = 32; o >= 1; o >>= 1) p += __shfl_xor(p, o);
        if (lane == 0) score[node] += p;
        uin = unext;
    }
}

// ---------- edge softmax + new_score ----------
__global__ __launch_bounds__(256) void edge_softmax_kernel(const float* __restrict__ score,
                                                           const int* __restrict__ rowptr,
                                                           const int* __restrict__ csr_src,
                                                           const float* __restrict__ bm,
                                                           float* __restrict__ nsf, int N) {
    int wid = (blockIdx.x * blockDim.x + threadIdx.x) >> 6;
    int lane = threadIdx.x & 63;
    if (wid >= N) return;
    float b = bm[0];
    float sd = score[wid] + b;
    int start = rowptr[wid];
    int end = rowptr[wid + 1];
    bool has0 = (start + lane < end);
    float ss0 = 0.f;
    float m = -INFINITY;
    if (has0) {
        ss0 = score[csr_src[start + lane]] + b;
        m = ss0 * sd;
    }
    for (int j = start + 64 + lane; j < end; j += 64) {
        float ss = score[csr_src[j]] + b;
        m = fmaxf(m, ss * sd);
    }
#pragma unroll
    for (int o = 32; o >= 1; o >>= 1) m = fmaxf(m, __shfl_xor(m, o));
    float se = 0.f, swe = 0.f;
    if (m > -INFINITY) {
        if (has0) {
            float e0 = expf(ss0 * sd - m);
            se += e0;
            swe += ss0 * e0;
        }
        for (int j = start + 64 + lane; j < end; j += 64) {
            float ss = score[csr_src[j]] + b;
            float e = expf(ss * sd - m);
            se += e;
            swe += ss * e;
        }
#pragma unroll
        for (int o = 32; o >= 1; o >>= 1) {
            se += __shfl_xor(se, o);
            swe += __shfl_xor(swe, o);
        }
    }
    float ns = (se > 0.f) ? (swe / se) : 0.f;
    if (lane == 0) nsf[wid] = sd + ns;
}

// ---------- fused graph-segment softmax: one block per graph ----------
__global__ __launch_bounds__(256) void graph_softmax_kernel(const float* __restrict__ nsf,
                                                            const int* __restrict__ batch,
                                                            float* __restrict__ out, int N) {
    int g = blockIdx.x;
    int tid = threadIdx.x;
    int lo = 0, hi = N;
    while (lo < hi) { int mid = (lo + hi) >> 1; if (batch[mid] < g) lo = mid + 1; else hi = mid; }
    int s0 = lo;
    hi = N;
    while (lo < hi) { int mid = (lo + hi) >> 1; if (batch[mid] < g + 1) lo = mid + 1; else hi = mid; }
    int s1 = lo;

    __shared__ float red[4];
    __shared__ float bval;
    float m = -INFINITY;
    for (int i = s0 + tid; i < s1; i += 256) m = fmaxf(m, nsf[i]);
#pragma unroll
    for (int o = 32; o >= 1; o >>= 1) m = fmaxf(m, __shfl_xor(m, o));
    if ((tid & 63) == 0) red[tid >> 6] = m;
    __syncthreads();
    if (tid == 0) bval = fmaxf(fmaxf(red[0], red[1]), fmaxf(red[2], red[3]));
    __syncthreads();
    float bm = bval;
    float s = 0.f;
    for (int i = s0 + tid; i < s1; i += 256) {
        float e = expf(nsf[i] - bm);
        out[i] = e;
        s += e;
    }
#pragma unroll
    for (int o = 32; o >= 1; o >>= 1) s += __shfl_xor(s, o);
    __syncthreads();
    if ((tid & 63) == 0) red[tid >> 6] = s;
    __syncthreads();
    if (tid == 0) bval = red[0] + red[1] + red[2] + red[3];
    __syncthreads();
    float inv = 1.f / bval;
    for (int i = s0 + tid; i < s1; i += 256) out[i] *= inv;
}

extern "C" void kernel_launch(void* const* d_in, const int* in_sizes, int n_in,
                              void* d_out, int out_size, void* d_ws, size_t ws_size,
                              hipStream_t stream) {
    const int N = N_NODES, E = N_EDGES;

    const float* x = (const float*)d_in[0];
    const int* ei = (const int*)d_in[1];
    const int* batch = (const int*)d_in[2];
    const float* W1a[3] = {(const float*)d_in[3], (const float*)d_in[7], (const float*)d_in[11]};
    const float* b1a[3] = {(const float*)d_in[4], (const float*)d_in[8], (const float*)d_in[12]};
    const float* W2a[3] = {(const float*)d_in[5], (const float*)d_in[9], (const float*)d_in[13]};
    const float* b2a[3] = {(const float*)d_in[6], (const float*)d_in[10], (const float*)d_in[14]};
    const float* Wm = (const float*)d_in[15];
    const float* bm = (const float*)d_in[16];
    float* out = (float*)d_out;

    const int* srcp = ei;
    const int* dstp = ei + E;

    // workspace layout (~62 MB)
    float* yA = (float*)d_ws;                   // N*64
    float* yB = yA + (size_t)N * 64;            // N*64
    float* ubuf = yB + (size_t)N * 64;          // N*64
    float* score = ubuf + (size_t)N * 64;       // N
    float* nsf = score + N;                     // N
    int* deg = (int*)(nsf + N);                 // N
    int* rowptr = deg + N;                      // N+1
    int* part = rowptr + N + 1;                 // 64
    int* csr_src = part + 64;                   // E
    uchar4* splits = (uchar4*)(csr_src + E);                      // N
    unsigned short* lr = (unsigned short*)(splits + N);           // E
    unsigned short* hist = lr + E;                                // CHUNKS*N
    unsigned short* base = hist + (size_t)CHUNKS * N;             // CHUNKS*N

    hist_kernel<<<CHUNKS, 1024, 0, stream>>>(dstp, hist, lr, E);

    const int nbScan = (N + 1023) / 1024;  // 49
    base_scan1_kernel<<<nbScan, 1024, 0, stream>>>(hist, base, deg, part, N);
    scan2_kernel<<<1, 64, 0, stream>>>(part, nbScan);
    scan3_kernel<<<nbScan, 1024, 0, stream>>>(deg, part, rowptr, N);

    fill_kernel<<<CHUNKS * FILL_SUB, 256, 0, stream>>>(srcp, dstp, lr, base, rowptr, csr_src, E);
    sort_csr_kernel<<<(N + 3) / 4, 256, 0, stream>>>(csr_src, rowptr, splits, N);

    const int gw = 4096;
    gemm0_kernel<<<1024, 256, 0, stream>>>(x, W1a[0], yA, N, gw);

    agg4_kernel<<<AGG_BLOCKS, 256, 0, stream>>>(yA, rowptr, csr_src, splits, ubuf, N);
    mlpAB_kernel<0><<<1024, 256, 0, stream>>>(ubuf, b1a[0], W2a[0], b2a[0], W1a[1], Wm, yB, score, N, gw);

    agg4_kernel<<<AGG_BLOCKS, 256, 0, stream>>>(yB, rowptr, csr_src, splits, ubuf, N);
    mlpAB_kernel<1><<<1024, 256, 0, stream>>>(ubuf, b1a[1], W2a[1], b2a[1], W1a[2], Wm, yA, score, N, gw);

    agg4_kernel<<<AGG_BLOCKS, 256, 0, stream>>>(yA, rowptr, csr_src, splits, ubuf, N);
    mlpA2_kernel<<<1024, 256, 0, stream>>>(ubuf, b1a[2], W2a[2], b2a[2], Wm, score, N, gw);

    edge_softmax_kernel<<<(N + 3) / 4, 256, 0, stream>>>(score, rowptr, csr_src, bm, nsf, N);

    graph_softmax_kernel<<<N_GRAPH, 256, 0, stream>>>(nsf, batch, out, N);
}

// Round 9
// 374.081 us; speedup vs baseline: 1.3123x; 1.1521x over previous
//
#include <hip/hip_runtime.h>
#include <math.h>

#define N_NODES 50000
#define N_EDGES 1600000
#define N_GRAPH 500
#define CHUNKS 64
#define EPC (N_EDGES / CHUNKS)  // 25000 edges per chunk

// ---------- helpers ----------
__device__ __forceinline__ float rl(float v, int k) {
    return __int_as_float(__builtin_amdgcn_readlane(__float_as_int(v), k));
}

// ---------- histsort: per-chunk LDS histogram -> in-LDS exclusive scan ->
//            chunk-local dst-sorted scatter. No global atomics.
//            Emits cntloc[c][d] = (cnt<<16)|loc  and csrc_chunk (dst-sorted per chunk).
__global__ __launch_bounds__(1024) void histsort_kernel(const int* __restrict__ src,
                                                        const int* __restrict__ dst,
                                                        int* __restrict__ csrc_chunk,
                                                        unsigned* __restrict__ cntloc,
                                                        unsigned short* __restrict__ lr_g) {
    __shared__ unsigned packed[N_NODES / 2];  // 100 KB: 2x16-bit counters, then prefixes
    __shared__ unsigned aux[1024];
    const int c = blockIdx.x;
    const int s0 = c * EPC;
    const int tid = threadIdx.x;

    for (int i = tid; i < N_NODES / 2; i += 1024) packed[i] = 0;
    __syncthreads();

    // count + per-edge local rank
    for (int e = s0 + tid; e < s0 + EPC; e += 1024) {
        int d = dst[e];
        int sh = (d & 1) * 16;
        unsigned old = atomicAdd(&packed[d >> 1], 1u << sh);
        lr_g[e] = (unsigned short)((old >> sh) & 0xffffu);
    }
    __syncthreads();

    // in-place exclusive scan over 50000 16-bit counters (prefix <= 25000, fits 16b)
    const int W = 25;  // words per thread (25 * 1024 >= 25000)
    int w0 = tid * W;
    int w1 = min(w0 + W, N_NODES / 2);
    unsigned run = 0;
    for (int i = w0; i < w1; i++) {
        unsigned v = packed[i];
        unsigned lo = v & 0xffffu, hi = v >> 16;
        packed[i] = run | ((run + lo) << 16);
        run += lo + hi;
    }
    aux[tid] = run;
    __syncthreads();
    for (int off = 1; off < 1024; off <<= 1) {
        unsigned t = (tid >= off) ? aux[tid - off] : 0;
        __syncthreads();
        aux[tid] += t;
        __syncthreads();
    }
    unsigned b0 = (tid == 0) ? 0 : aux[tid - 1];
    if (b0) {
        unsigned addv = b0 | (b0 << 16);  // no cross-field carry: prefixes <= 50000/2 per field
        for (int i = w0; i < w1; i++) packed[i] += addv;
    }
    __syncthreads();

    // scatter this chunk's edges into chunk-local dst-sorted order (single-block region)
    int* outc = csrc_chunk + (size_t)c * EPC;
    for (int e = s0 + tid; e < s0 + EPC; e += 1024) {
        int d = dst[e];
        unsigned pw = packed[d >> 1];
        unsigned loc = (d & 1) ? (pw >> 16) : (pw & 0xffffu);
        outc[loc + lr_g[e]] = src[e];
    }
    // emit (cnt,loc) per node
    unsigned* clc = cntloc + (size_t)c * N_NODES;
    for (int d = tid; d < N_NODES; d += 1024) {
        unsigned pw = packed[d >> 1];
        unsigned loc = (d & 1) ? (pw >> 16) : (pw & 0xffffu);
        unsigned nxt;
        if (d + 1 < N_NODES) {
            unsigned pw2 = packed[(d + 1) >> 1];
            nxt = ((d + 1) & 1) ? (pw2 >> 16) : (pw2 & 0xffffu);
        } else {
            nxt = EPC;
        }
        clc[d] = ((nxt - loc) << 16) | loc;
    }
}

// ---------- base + scan1 fused: per-node cross-chunk scan of cnt -> base, deg; block sums
__global__ __launch_bounds__(1024) void base_scan1_kernel(const unsigned* __restrict__ cntloc,
                                                          unsigned short* __restrict__ base,
                                                          int* __restrict__ deg,
                                                          int* __restrict__ part, int N) {
    int d = blockIdx.x * 1024 + threadIdx.x;
    int run = 0;
    if (d < N) {
#pragma unroll 8
        for (int c = 0; c < CHUNKS; c++) {
            int v = (int)(cntloc[(size_t)c * N + d] >> 16);
            base[(size_t)c * N + d] = (unsigned short)run;
            run += v;
        }
        deg[d] = run;
    }
    int v = run;
#pragma unroll
    for (int o = 32; o >= 1; o >>= 1) v += __shfl_xor(v, o);
    __shared__ int red[16];
    if ((threadIdx.x & 63) == 0) red[threadIdx.x >> 6] = v;
    __syncthreads();
    if (threadIdx.x == 0) {
        int s = 0;
#pragma unroll
        for (int k = 0; k < 16; k++) s += red[k];
        part[blockIdx.x] = s;
    }
}

__global__ void scan2_kernel(int* __restrict__ part, int nb) {
    int lane = threadIdx.x;
    int v = (lane < nb) ? part[lane] : 0;
    int orig = v;
#pragma unroll
    for (int o = 1; o < 64; o <<= 1) {
        int t = __shfl_up(v, o);
        if (lane >= o) v += t;
    }
    if (lane < nb) part[lane] = v - orig;
    if (lane == nb - 1) part[nb] = v;
}

__global__ __launch_bounds__(1024) void scan3_kernel(const int* __restrict__ deg,
                                                     const int* __restrict__ part,
                                                     int* __restrict__ rowptr, int N) {
    int i = blockIdx.x * 1024 + threadIdx.x;
    int lane = threadIdx.x & 63;
    int w = threadIdx.x >> 6;
    int v = (i < N) ? deg[i] : 0;
    int inc = v;
#pragma unroll
    for (int o = 1; o < 64; o <<= 1) {
        int t = __shfl_up(inc, o);
        if (lane >= o) inc += t;
    }
    __shared__ int wsum[16];
    if (lane == 63) wsum[w] = inc;
    __syncthreads();
    if (threadIdx.x < 16) {
        int x = wsum[threadIdx.x];
        int xo = x;
#pragma unroll
        for (int o = 1; o < 16; o <<= 1) {
            int t = __shfl_up(x, o);
            if ((int)threadIdx.x >= o) x += t;
        }
        wsum[threadIdx.x] = x - xo;
    }
    __syncthreads();
    int b = part[blockIdx.x] + wsum[w];
    if (i < N) {
        rowptr[i] = b + inc - v;
        if (i == N - 1) rowptr[N] = b + inc;
    }
}

// ---------- gatherfill: one wave per node, lane = chunk; node-contiguous writes ----------
__global__ __launch_bounds__(256) void gatherfill_kernel(const int* __restrict__ csrc_chunk,
                                                         const unsigned* __restrict__ cntloc,
                                                         const unsigned short* __restrict__ base,
                                                         const int* __restrict__ rowptr,
                                                         int* __restrict__ csr_src) {
    // XCD-swizzle: contiguous node range per XCD for cntloc/base L2 locality
    const int perXcd = N_NODES / 8;  // 6250
    int xcd = blockIdx.x & 7;
    int idx = (blockIdx.x >> 3) * 4 + ((threadIdx.x) >> 6);
    if (idx >= perXcd) return;
    int wid = xcd * perXcd + idx;
    int lane = threadIdx.x & 63;  // chunk id (CHUNKS == 64)
    unsigned cl = cntloc[(size_t)lane * N_NODES + wid];
    int cnt = (int)(cl >> 16);
    int loc = (int)(cl & 0xffffu);
    int ob = rowptr[wid] + (int)base[(size_t)lane * N_NODES + wid];
    const int* in = csrc_chunk + (size_t)lane * EPC + loc;
    for (int i = 0; i < cnt; i++) csr_src[ob + i] = in[i];
}

// ---------- aggregation (R6 flat version): float4 lanes, 8 loads in flight ----------
__global__ __launch_bounds__(256) void agg_kernel(const float* __restrict__ y,
                                                  const int* __restrict__ rowptr,
                                                  const int* __restrict__ csr_src,
                                                  float* __restrict__ u, int N) {
    int wid = (blockIdx.x * 256 + threadIdx.x) >> 6;
    int lane = threadIdx.x & 63;
    if (wid >= N) return;
    int q = lane >> 4;   // edge slot 0..3
    int r = lane & 15;   // feature quad 0..15
    int start = rowptr[wid];
    int end = rowptr[wid + 1];
    float4 acc = make_float4(0.f, 0.f, 0.f, 0.f);
    int j = start;
    for (; j + 32 <= end; j += 32) {
        int s0 = csr_src[j + q];
        int s1 = csr_src[j + 4 + q];
        int s2 = csr_src[j + 8 + q];
        int s3 = csr_src[j + 12 + q];
        int s4 = csr_src[j + 16 + q];
        int s5 = csr_src[j + 20 + q];
        int s6 = csr_src[j + 24 + q];
        int s7 = csr_src[j + 28 + q];
        float4 v0 = *(const float4*)(y + (size_t)s0 * 64 + r * 4);
        float4 v1 = *(const float4*)(y + (size_t)s1 * 64 + r * 4);
        float4 v2 = *(const float4*)(y + (size_t)s2 * 64 + r * 4);
        float4 v3 = *(const float4*)(y + (size_t)s3 * 64 + r * 4);
        float4 v4 = *(const float4*)(y + (size_t)s4 * 64 + r * 4);
        float4 v5 = *(const float4*)(y + (size_t)s5 * 64 + r * 4);
        float4 v6 = *(const float4*)(y + (size_t)s6 * 64 + r * 4);
        float4 v7 = *(const float4*)(y + (size_t)s7 * 64 + r * 4);
        acc.x += ((v0.x + v1.x) + (v2.x + v3.x)) + ((v4.x + v5.x) + (v6.x + v7.x));
        acc.y += ((v0.y + v1.y) + (v2.y + v3.y)) + ((v4.y + v5.y) + (v6.y + v7.y));
        acc.z += ((v0.z + v1.z) + (v2.z + v3.z)) + ((v4.z + v5.z) + (v6.z + v7.z));
        acc.w += ((v0.w + v1.w) + (v2.w + v3.w)) + ((v4.w + v5.w) + (v6.w + v7.w));
    }
#pragma unroll
    for (int m = 0; m < 8; m++) {
        int e = j + 4 * m + q;
        if (e < end) {
            int s = csr_src[e];
            float4 v = *(const float4*)(y + (size_t)s * 64 + r * 4);
            acc.x += v.x; acc.y += v.y; acc.z += v.z; acc.w += v.w;
        }
    }
    acc.x += __shfl_xor(acc.x, 16);
    acc.y += __shfl_xor(acc.y, 16);
    acc.z += __shfl_xor(acc.z, 16);
    acc.w += __shfl_xor(acc.w, 16);
    acc.x += __shfl_xor(acc.x, 32);
    acc.y += __shfl_xor(acc.y, 32);
    acc.z += __shfl_xor(acc.z, 32);
    acc.w += __shfl_xor(acc.w, 32);
    if (lane < 16) {
        float4 self = *(const float4*)(y + (size_t)wid * 64 + r * 4);
        acc.x += self.x; acc.y += self.y; acc.z += self.z; acc.w += self.w;
        *(float4*)(u + (size_t)wid * 64 + r * 4) = acc;
    }
}

// ---------- gemm0: y0 = x @ W1_0 (N x 128 -> N x 64), register weights ----------
__global__ __launch_bounds__(256) void gemm0_kernel(const float* __restrict__ x,
                                                    const float* __restrict__ W1,
                                                    float* __restrict__ y0,
                                                    int N, int totalWaves) {
    int lane = threadIdx.x & 63;
    int wid = (blockIdx.x * 256 + threadIdx.x) >> 6;
    float w[64];
#pragma unroll
    for (int k = 0; k < 64; k++) w[k] = W1[k * 64 + lane];
    for (int node = wid; node < N; node += totalWaves) {
        float xa = x[node * 128 + lane];
        float a0 = 0.f, a1 = 0.f, a2 = 0.f, a3 = 0.f;
#pragma unroll
        for (int k = 0; k < 64; k += 4) {
            a0 = fmaf(rl(xa, k + 0), w[k + 0], a0);
            a1 = fmaf(rl(xa, k + 1), w[k + 1], a1);
            a2 = fmaf(rl(xa, k + 2), w[k + 2], a2);
            a3 = fmaf(rl(xa, k + 3), w[k + 3], a3);
        }
        y0[node * 64 + lane] = (a0 + a1) + (a2 + a3);
    }
#pragma unroll
    for (int k = 0; k < 64; k++) w[k] = W1[(64 + k) * 64 + lane];
    for (int node = wid; node < N; node += totalWaves) {
        float xb = x[node * 128 + 64 + lane];
        float a0 = 0.f, a1 = 0.f, a2 = 0.f, a3 = 0.f;
#pragma unroll
        for (int k = 0; k < 64; k += 4) {
            a0 = fmaf(rl(xb, k + 0), w[k + 0], a0);
            a1 = fmaf(rl(xb, k + 1), w[k + 1], a1);
            a2 = fmaf(rl(xb, k + 2), w[k + 2], a2);
            a3 = fmaf(rl(xb, k + 3), w[k + 3], a3);
        }
        y0[node * 64 + lane] += (a0 + a1) + (a2 + a3);
    }
}

// ---------- fused mlpAB (layers 0,1) ----------
template <int LAYER>
__global__ __launch_bounds__(256) void mlpAB_kernel(const float* __restrict__ u,
                                                    const float* __restrict__ b1,
                                                    const float* __restrict__ W2,
                                                    const float* __restrict__ b2,
                                                    const float* __restrict__ W1n,
                                                    const float* __restrict__ Wm,
                                                    float* __restrict__ ynext,
                                                    float* __restrict__ score,
                                                    int N, int totalWaves) {
    int lane = threadIdx.x & 63;
    int wid = (blockIdx.x * 256 + threadIdx.x) >> 6;
    float w2[64], w1[64];
#pragma unroll
    for (int k = 0; k < 64; k++) w2[k] = W2[k * 64 + lane];
#pragma unroll
    for (int k = 0; k < 64; k++) w1[k] = W1n[k * 64 + lane];
    float bb1 = b1[lane], bb2 = b2[lane], wm = Wm[LAYER * 64 + lane];

    int node = wid;
    float uin = (node < N) ? u[node * 64 + lane] : 0.f;
    for (; node < N; node += totalWaves) {
        int nn = node + totalWaves;
        float unext = (nn < N) ? u[nn * 64 + lane] : 0.f;
        float t = fmaxf(uin + bb1, 0.f);
        float a0 = 0.f, a1 = 0.f, a2 = 0.f, a3 = 0.f;
#pragma unroll
        for (int k = 0; k < 64; k += 4) {
            a0 = fmaf(rl(t, k + 0), w2[k + 0], a0);
            a1 = fmaf(rl(t, k + 1), w2[k + 1], a1);
            a2 = fmaf(rl(t, k + 2), w2[k + 2], a2);
            a3 = fmaf(rl(t, k + 3), w2[k + 3], a3);
        }
        float h = fmaxf(bb2 + ((a0 + a1) + (a2 + a3)), 0.f);
        float p = h * wm;
#pragma unroll
        for (int o = 32; o >= 1; o >>= 1) p += __shfl_xor(p, o);
        if (lane == 0) {
            if (LAYER == 0) score[node] = p;
            else score[node] += p;
        }
        float y0 = 0.f, y1 = 0.f, y2 = 0.f, y3 = 0.f;
#pragma unroll
        for (int k = 0; k < 64; k += 4) {
            y0 = fmaf(rl(h, k + 0), w1[k + 0], y0);
            y1 = fmaf(rl(h, k + 1), w1[k + 1], y1);
            y2 = fmaf(rl(h, k + 2), w1[k + 2], y2);
            y3 = fmaf(rl(h, k + 3), w1[k + 3], y3);
        }
        ynext[node * 64 + lane] = (y0 + y1) + (y2 + y3);
        uin = unext;
    }
}

// ---------- mlpA2 (layer 2) ----------
__global__ __launch_bounds__(256) void mlpA2_kernel(const float* __restrict__ u,
                                                    const float* __restrict__ b1,
                                                    const float* __restrict__ W2,
                                                    const float* __restrict__ b2,
                                                    const float* __restrict__ Wm,
                                                    float* __restrict__ score,
                                                    int N, int totalWaves) {
    int lane = threadIdx.x & 63;
    int wid = (blockIdx.x * 256 + threadIdx.x) >> 6;
    float w2[64];
#pragma unroll
    for (int k = 0; k < 64; k++) w2[k] = W2[k * 64 + lane];
    float bb1 = b1[lane], bb2 = b2[lane], wm = Wm[2 * 64 + lane];

    int node = wid;
    float uin = (node < N) ? u[node * 64 + lane] : 0.f;
    for (; node < N; node += totalWaves) {
        int nn = node + totalWaves;
        float unext = (nn < N) ? u[nn * 64 + lane] : 0.f;
        float t = fmaxf(uin + bb1, 0.f);
        float a0 = 0.f, a1 = 0.f, a2 = 0.f, a3 = 0.f;
#pragma unroll
        for (int k = 0; k < 64; k += 4) {
            a0 = fmaf(rl(t, k + 0), w2[k + 0], a0);
            a1 = fmaf(rl(t, k + 1), w2[k + 1], a1);
            a2 = fmaf(rl(t, k + 2), w2[k + 2], a2);
            a3 = fmaf(rl(t, k + 3), w2[k + 3], a3);
        }
        float h = bb2 + ((a0 + a1) + (a2 + a3));
        float p = h * wm;
#pragma unroll
        for (int o = 32; o >= 1; o >>= 1) p += __shfl_xor(p, o);
        if (lane == 0) score[node] += p;
        uin = unext;
    }
}

// ---------- edge softmax + new_score ----------
__global__ __launch_bounds__(256) void edge_softmax_kernel(const float* __restrict__ score,
                                                           const int* __restrict__ rowptr,
                                                           const int* __restrict__ csr_src,
                                                           const float* __restrict__ bm,
                                                           float* __restrict__ nsf, int N) {
    int wid = (blockIdx.x * blockDim.x + threadIdx.x) >> 6;
    int lane = threadIdx.x & 63;
    if (wid >= N) return;
    float b = bm[0];
    float sd = score[wid] + b;
    int start = rowptr[wid];
    int end = rowptr[wid + 1];
    bool has0 = (start + lane < end);
    float ss0 = 0.f;
    float m = -INFINITY;
    if (has0) {
        ss0 = score[csr_src[start + lane]] + b;
        m = ss0 * sd;
    }
    for (int j = start + 64 + lane; j < end; j += 64) {
        float ss = score[csr_src[j]] + b;
        m = fmaxf(m, ss * sd);
    }
#pragma unroll
    for (int o = 32; o >= 1; o >>= 1) m = fmaxf(m, __shfl_xor(m, o));
    float se = 0.f, swe = 0.f;
    if (m > -INFINITY) {
        if (has0) {
            float e0 = expf(ss0 * sd - m);
            se += e0;
            swe += ss0 * e0;
        }
        for (int j = start + 64 + lane; j < end; j += 64) {
            float ss = score[csr_src[j]] + b;
            float e = expf(ss * sd - m);
            se += e;
            swe += ss * e;
        }
#pragma unroll
        for (int o = 32; o >= 1; o >>= 1) {
            se += __shfl_xor(se, o);
            swe += __shfl_xor(swe, o);
        }
    }
    float ns = (se > 0.f) ? (swe / se) : 0.f;
    if (lane == 0) nsf[wid] = sd + ns;
}

// ---------- fused graph-segment softmax: one block per graph ----------
__global__ __launch_bounds__(256) void graph_softmax_kernel(const float* __restrict__ nsf,
                                                            const int* __restrict__ batch,
                                                            float* __restrict__ out, int N) {
    int g = blockIdx.x;
    int tid = threadIdx.x;
    int lo = 0, hi = N;
    while (lo < hi) { int mid = (lo + hi) >> 1; if (batch[mid] < g) lo = mid + 1; else hi = mid; }
    int s0 = lo;
    hi = N;
    while (lo < hi) { int mid = (lo + hi) >> 1; if (batch[mid] < g + 1) lo = mid + 1; else hi = mid; }
    int s1 = lo;

    __shared__ float red[4];
    __shared__ float bval;
    float m = -INFINITY;
    for (int i = s0 + tid; i < s1; i += 256) m = fmaxf(m, nsf[i]);
#pragma unroll
    for (int o = 32; o >= 1; o >>= 1) m = fmaxf(m, __shfl_xor(m, o));
    if ((tid & 63) == 0) red[tid >> 6] = m;
    __syncthreads();
    if (tid == 0) bval = fmaxf(fmaxf(red[0], red[1]), fmaxf(red[2], red[3]));
    __syncthreads();
    float bmx = bval;
    float s = 0.f;
    for (int i = s0 + tid; i < s1; i += 256) {
        float e = expf(nsf[i] - bmx);
        out[i] = e;
        s += e;
    }
#pragma unroll
    for (int o = 32; o >= 1; o >>= 1) s += __shfl_xor(s, o);
    __syncthreads();
    if ((tid & 63) == 0) red[tid >> 6] = s;
    __syncthreads();
    if (tid == 0) bval = red[0] + red[1] + red[2] + red[3];
    __syncthreads();
    float inv = 1.f / bval;
    for (int i = s0 + tid; i < s1; i += 256) out[i] *= inv;
}

extern "C" void kernel_launch(void* const* d_in, const int* in_sizes, int n_in,
                              void* d_out, int out_size, void* d_ws, size_t ws_size,
                              hipStream_t stream) {
    const int N = N_NODES, E = N_EDGES;

    const float* x = (const float*)d_in[0];
    const int* ei = (const int*)d_in[1];
    const int* batch = (const int*)d_in[2];
    const float* W1a[3] = {(const float*)d_in[3], (const float*)d_in[7], (const float*)d_in[11]};
    const float* b1a[3] = {(const float*)d_in[4], (const float*)d_in[8], (const float*)d_in[12]};
    const float* W2a[3] = {(const float*)d_in[5], (const float*)d_in[9], (const float*)d_in[13]};
    const float* b2a[3] = {(const float*)d_in[6], (const float*)d_in[10], (const float*)d_in[14]};
    const float* Wm = (const float*)d_in[15];
    const float* bm = (const float*)d_in[16];
    float* out = (float*)d_out;

    const int* srcp = ei;
    const int* dstp = ei + E;

    // workspace layout (~67 MB; csrc_chunk aliases ubuf, which is first used after gatherfill)
    float* yA = (float*)d_ws;                   // N*64
    float* yB = yA + (size_t)N * 64;            // N*64
    float* ubuf = yB + (size_t)N * 64;          // N*64  (aliases csrc_chunk)
    int* csrc_chunk = (int*)ubuf;               // E ints (6.4MB of ubuf's 12.8MB)
    float* score = ubuf + (size_t)N * 64;       // N
    float* nsf = score + N;                     // N
    int* deg = (int*)(nsf + N);                 // N
    int* rowptr = deg + N;                      // N+1
    int* part = rowptr + N + 1;                 // 64
    int* csr_src = part + 64;                   // E
    unsigned* cntloc = (unsigned*)(csr_src + E);                  // CHUNKS*N u32
    unsigned short* base = (unsigned short*)(cntloc + (size_t)CHUNKS * N);  // CHUNKS*N u16
    unsigned short* lr = base + (size_t)CHUNKS * N;               // E u16

    histsort_kernel<<<CHUNKS, 1024, 0, stream>>>(srcp, dstp, csrc_chunk, cntloc, lr);

    const int nbScan = (N + 1023) / 1024;  // 49
    base_scan1_kernel<<<nbScan, 1024, 0, stream>>>(cntloc, base, deg, part, N);
    scan2_kernel<<<1, 64, 0, stream>>>(part, nbScan);
    scan3_kernel<<<nbScan, 1024, 0, stream>>>(deg, part, rowptr, N);

    const int gfBlocks = 8 * ((N / 8 + 3) / 4);  // 8 XCD ranges x 1563 blocks
    gatherfill_kernel<<<gfBlocks, 256, 0, stream>>>(csrc_chunk, cntloc, base, rowptr, csr_src);

    const int gw = 4096;
    gemm0_kernel<<<1024, 256, 0, stream>>>(x, W1a[0], yA, N, gw);

    int aggBlocks = (N + 3) / 4;

    agg_kernel<<<aggBlocks, 256, 0, stream>>>(yA, rowptr, csr_src, ubuf, N);
    mlpAB_kernel<0><<<1024, 256, 0, stream>>>(ubuf, b1a[0], W2a[0], b2a[0], W1a[1], Wm, yB, score, N, gw);

    agg_kernel<<<aggBlocks, 256, 0, stream>>>(yB, rowptr, csr_src, ubuf, N);
    mlpAB_kernel<1><<<1024, 256, 0, stream>>>(ubuf, b1a[1], W2a[1], b2a[1], W1a[2], Wm, yA, score, N, gw);

    agg_kernel<<<aggBlocks, 256, 0, stream>>>(yA, rowptr, csr_src, ubuf, N);
    mlpA2_kernel<<<1024, 256, 0, stream>>>(ubuf, b1a[2], W2a[2], b2a[2], Wm, score, N, gw);

    edge_softmax_kernel<<<(N + 3) / 4, 256, 0, stream>>>(score, rowptr, csr_src, bm, nsf, N);

    graph_softmax_kernel<<<N_GRAPH, 256, 0, stream>>>(nsf, batch, out, N);
}